// Round 5
// baseline (4019.285 us; speedup 1.0000x reference)
//
#include <hip/hip_runtime.h>
#include <hip/hip_bf16.h>
#include <math.h>

#define T_LEN 512
#define LAT   1024
#define D_DIM 512
#define NH    8
#define HD    64
#define FF_D  2048
#define NL    8
#define NQ    16

// ---------------------------------------------------------------------------
// Workspace layout (float offsets)
// ---------------------------------------------------------------------------
#define WS_QFPRE    0
#define WS_G        131072
#define WS_QF       2097152
#define WS_TA       2621440
#define WS_HIDG     3145728            // 2048 guard floats before hidden
#define WS_HID      3147776
#define WS_CONV     3672064
#define WS_H        4196352
#define WS_X        4458496
#define WS_QB       4720640
#define WS_KB       4982784
#define WS_VB       5244928
#define WS_ATT      5507072
#define WS_FF       5769216
#define WS_BSUM     6817792
#define WS_HOUT     6819840            // guard 1024 at 6818816, post at 7344128
#define WS_UP       7348224            // guard 3072 at 7345152, post at 8396800
#define WS_DEC0     8400384            // guard 512  at 8399872, post at 8924672
#define WS_T1       8925440            // guard 256  at 8925184, post at 11022592
#define WS_T2       11022976           // guard 128  at 11022848, post at 17314432
#define WS_W2UP     17314560           // 6291456
#define WS_W2D1     23606016           // 3145728
#define WS_W2D2     26751744           // 589824
#define WS_W2D3     27341568           // 122880
#define WS_T3       31457344           // guard 64 at 31457280, post at 47185984
#define WS_W2D4     47186048           // 24576 -> ends 47210624
#define WS_T4       0                  // aliases phase-A region (dead by then)
#define WS_PART     31457344           // split-K partials alias t3 data region

// ---------------------------------------------------------------------------
// Zero the guard rows (ws is poisoned 0xAA before every launch)
// ---------------------------------------------------------------------------
__global__ void k_zero_guards(float* __restrict__ ws) {
    const int offs[13] = {3145728, 6818816, 7344128, 7345152, 8396800,
                          8399872, 8924672, 8925184, 11022592, 11022848,
                          17314432, 31457280, 47185984};
    const int lens[13] = {2048, 1024, 1024, 3072, 3072,
                          512, 512, 256, 256, 128,
                          128, 64, 64};
    int r = blockIdx.x;
    for (int i = threadIdx.x; i < lens[r]; i += 256) ws[offs[r] + i] = 0.f;
}

// ---------------------------------------------------------------------------
// Gathers
// ---------------------------------------------------------------------------
__global__ __launch_bounds__(256) void k_gather(const int* __restrict__ codes,
                                                const float* __restrict__ emb_first,
                                                const float* __restrict__ emb_rest,
                                                float* __restrict__ qf_pre,
                                                float* __restrict__ G) {
    int idx = blockIdx.x * 256 + threadIdx.x;
    int c = idx & 255;
    int r = (idx >> 8) & 15;
    int t = idx >> 12;
    if (t >= T_LEN) return;
    if (r == 0) {
        int code = codes[t];
        qf_pre[t * 256 + c] = emb_first[code * 256 + c];
    } else {
        int n = r - 1;
        int code = codes[(n + 1) * T_LEN + t];
        G[t * 3840 + n * 256 + c] = emb_rest[(n * 2048 + code) * 256 + c];
    }
}

__global__ void k_bias_sum(const float* __restrict__ pr_b, float* __restrict__ out) {
    int d = blockIdx.x * 256 + threadIdx.x;
    if (d >= LAT) return;
    float s = 0.f;
    for (int n = 0; n < NQ - 1; n++) s += pr_b[n * LAT + d];
    out[d] = s;
}

// ---------------------------------------------------------------------------
// convT weight transform (K=2s): W2[(j*Cin+ci), p*Cout+co], j in 0..2 (d=j-1)
// ---------------------------------------------------------------------------
__global__ __launch_bounds__(256) void k_wt(const float* __restrict__ w,
                                            float* __restrict__ W2,
                                            int Cin, int Cout, int s, int pad_a) {
    int idx = blockIdx.x * 256 + threadIdx.x;
    int N = s * Cout;
    int total = 3 * Cin * N;
    if (idx >= total) return;
    int col = idx % N;
    int rowk = idx / N;
    int j = rowk / Cin, ci = rowk % Cin;
    int p = col / Cout, co = col % Cout;
    int kk0 = (pad_a - p) % s;
    if (kk0 < 0) kk0 += s;
    int cp = (p + kk0 - pad_a) / s;
    int d = j - 1;
    float v = 0.f;
    if (d == cp) v = w[((size_t)kk0 * Cin + ci) * Cout + co];
    else if (d == cp + 1) v = w[((size_t)(kk0 + s) * Cin + ci) * Cout + co];
    W2[idx] = v;
}

// ---------------------------------------------------------------------------
// GEMM core v2: TM x TN tile, 256 threads, microtile (TM/16)x(TN/16),
// double-buffered LDS, float4 global staging, float4 LDS B-writes,
// BK=16, one barrier per k-step.
// ---------------------------------------------------------------------------
template <int TM, int TN>
__device__ __forceinline__ void gemm_core2(const float* __restrict__ A, int lda,
                                           const float* __restrict__ B, int N,
                                           int klen, int m0, int n0,
                                           float (&acc)[TM / 16][TN / 16]) {
    constexpr int RM = TM / 16, RN = TN / 16;
    constexpr int NA4 = TM / 64;      // float4 A-loads per thread
    constexpr int NB4 = TN / 64;      // float4 B-loads per thread
    constexpr int BCQ = TN / 4;       // B float4s per LDS row
    __shared__ float As[2][16][TM + 4];
    __shared__ float Bs[2][16][TN + 4];
    int tid = threadIdx.x;
    int tx = tid & 15, ty = tid >> 4;
    int arow[NA4], akq[NA4], bkk[NB4], bcq[NB4];
#pragma unroll
    for (int i = 0; i < NA4; i++) {
        int idx = tid + 256 * i;
        arow[i] = idx >> 2; akq[i] = idx & 3;
    }
#pragma unroll
    for (int i = 0; i < NB4; i++) {
        int idx = tid + 256 * i;
        bkk[i] = idx / BCQ; bcq[i] = idx % BCQ;
    }
    float4 av[NA4], bv[NB4];
#pragma unroll
    for (int i = 0; i < NA4; i++)
        av[i] = *(const float4*)&A[(size_t)(m0 + arow[i]) * lda + akq[i] * 4];
#pragma unroll
    for (int i = 0; i < NB4; i++)
        bv[i] = *(const float4*)&B[(size_t)bkk[i] * N + n0 + bcq[i] * 4];
#pragma unroll
    for (int i = 0; i < NA4; i++) {
        As[0][akq[i] * 4 + 0][arow[i]] = av[i].x;
        As[0][akq[i] * 4 + 1][arow[i]] = av[i].y;
        As[0][akq[i] * 4 + 2][arow[i]] = av[i].z;
        As[0][akq[i] * 4 + 3][arow[i]] = av[i].w;
    }
#pragma unroll
    for (int i = 0; i < NB4; i++)
        *(float4*)&Bs[0][bkk[i]][bcq[i] * 4] = bv[i];
    __syncthreads();
    int nk = klen >> 4;
    for (int t = 0; t < nk; t++) {
        int cur = t & 1;
        if (t + 1 < nk) {
            int k0 = (t + 1) << 4;
#pragma unroll
            for (int i = 0; i < NA4; i++)
                av[i] = *(const float4*)&A[(size_t)(m0 + arow[i]) * lda + k0 + akq[i] * 4];
#pragma unroll
            for (int i = 0; i < NB4; i++)
                bv[i] = *(const float4*)&B[(size_t)(k0 + bkk[i]) * N + n0 + bcq[i] * 4];
        }
#pragma unroll
        for (int kk = 0; kk < 16; kk++) {
            float a[RM], b[RN];
#pragma unroll
            for (int i = 0; i < RM / 4; i++)
                *(float4*)&a[4 * i] = *(const float4*)&As[cur][kk][ty * RM + 4 * i];
#pragma unroll
            for (int j = 0; j < RN / 4; j++)
                *(float4*)&b[4 * j] = *(const float4*)&Bs[cur][kk][tx * RN + 4 * j];
#pragma unroll
            for (int i = 0; i < RM; i++)
#pragma unroll
                for (int j = 0; j < RN; j++) acc[i][j] += a[i] * b[j];
        }
        if (t + 1 < nk) {
            int nxt = cur ^ 1;
#pragma unroll
            for (int i = 0; i < NA4; i++) {
                As[nxt][akq[i] * 4 + 0][arow[i]] = av[i].x;
                As[nxt][akq[i] * 4 + 1][arow[i]] = av[i].y;
                As[nxt][akq[i] * 4 + 2][arow[i]] = av[i].z;
                As[nxt][akq[i] * 4 + 3][arow[i]] = av[i].w;
            }
#pragma unroll
            for (int i = 0; i < NB4; i++)
                *(float4*)&Bs[nxt][bkk[i]][bcq[i] * 4] = bv[i];
            __syncthreads();
        }
    }
}

__device__ __forceinline__ float apply_act(float v, int act) {
    if (act == 1) return 0.5f * v * (1.0f + erff(v * 0.70710678118654752440f));
    if (act == 2) return v > 0.f ? v : expm1f(v);
    return v;
}

// If part != null: raw partial write to part + z*mn (epilogue in k_reduce).
template <int TM, int TN>
__global__ __launch_bounds__(256) void k_gemm3(const float* __restrict__ A, int lda,
                                               const float* __restrict__ B,
                                               const float* __restrict__ bias, unsigned bmask,
                                               const float* __restrict__ res,
                                               const float* __restrict__ scale,
                                               float* __restrict__ C,
                                               float* __restrict__ part, long mn,
                                               int N, int klen, int act) {
    constexpr int RM = TM / 16, RN = TN / 16;
    float acc[RM][RN] = {};
    int m0 = blockIdx.x * TM, n0 = blockIdx.y * TN;
    int kz = blockIdx.z * klen;
    gemm_core2<TM, TN>(A + kz, lda, B + (size_t)kz * N, N, klen, m0, n0, acc);
    int tid = threadIdx.x;
    int tx = tid & 15, ty = tid >> 4;
    if (part) {
        float* out = part + (size_t)blockIdx.z * mn;
#pragma unroll
        for (int i = 0; i < RM; i++) {
            size_t rb = (size_t)(m0 + ty * RM + i) * N + n0 + tx * RN;
#pragma unroll
            for (int j = 0; j < RN / 4; j++)
                *(float4*)&out[rb + 4 * j] = make_float4(acc[i][4 * j], acc[i][4 * j + 1],
                                                         acc[i][4 * j + 2], acc[i][4 * j + 3]);
        }
    } else {
#pragma unroll
        for (int i = 0; i < RM; i++) {
            int row = m0 + ty * RM + i;
            size_t rb = (size_t)row * N;
#pragma unroll
            for (int j = 0; j < RN; j++) {
                int col = n0 + tx * RN + j;
                float v = acc[i][j];
                if (bias) v += bias[col & bmask];
                v = apply_act(v, act);
                if (scale) v *= scale[col];
                if (res) v += res[rb + col];
                acc[i][j] = v;
            }
#pragma unroll
            for (int j = 0; j < RN / 4; j++)
                *(float4*)&C[rb + n0 + tx * RN + 4 * j] =
                    make_float4(acc[i][4 * j], acc[i][4 * j + 1],
                                acc[i][4 * j + 2], acc[i][4 * j + 3]);
        }
    }
}

// Fused QKV with split-K=2: z = which*2 + s; raw partials.
__global__ __launch_bounds__(256) void k_qkv(const float* __restrict__ A,
                                             const float* __restrict__ B0,
                                             const float* __restrict__ B1,
                                             const float* __restrict__ B2,
                                             float* __restrict__ part) {
    int which = blockIdx.z >> 1, s = blockIdx.z & 1;
    const float* B = which == 0 ? B0 : (which == 1 ? B1 : B2);
    float acc[4][4] = {};
    int m0 = blockIdx.x * 64, n0 = blockIdx.y * 64;
    int kz = s * 256;
    gemm_core2<64, 64>(A + kz, 512, B + (size_t)kz * 512, 512, 256, m0, n0, acc);
    int tid = threadIdx.x;
    int tx = tid & 15, ty = tid >> 4;
    float* out = part + (size_t)blockIdx.z * (512 * 512);
#pragma unroll
    for (int i = 0; i < 4; i++)
        *(float4*)&out[(size_t)(m0 + ty * 4 + i) * 512 + n0 + tx * 4] =
            make_float4(acc[i][0], acc[i][1], acc[i][2], acc[i][3]);
}

// ---------------------------------------------------------------------------
// Split-K reduce + epilogue (bias -> act -> scale -> res)
// ---------------------------------------------------------------------------
__global__ __launch_bounds__(256) void k_reduce(const float* __restrict__ part, long mn, int S,
                                                const float* __restrict__ bias, unsigned bmask,
                                                const float* __restrict__ res,
                                                const float* __restrict__ scale,
                                                float* __restrict__ C, int N, int act) {
    long idx = ((long)blockIdx.x * 256 + threadIdx.x) * 4;
    if (idx >= mn) return;
    float4 v = *(const float4*)(part + idx);
    for (int s2 = 1; s2 < S; s2++) {
        float4 u = *(const float4*)(part + (size_t)s2 * mn + idx);
        v.x += u.x; v.y += u.y; v.z += u.z; v.w += u.w;
    }
    int col = (int)(idx % N);
    float vv[4] = {v.x, v.y, v.z, v.w};
#pragma unroll
    for (int j = 0; j < 4; j++) {
        float t = vv[j];
        int c = col + j;
        if (bias) t += bias[c & bmask];
        t = apply_act(t, act);
        if (scale) t *= scale[c];
        if (res) t += res[idx + j];
        vv[j] = t;
    }
    *(float4*)(C + idx) = make_float4(vv[0], vv[1], vv[2], vv[3]);
}

__global__ __launch_bounds__(256) void k_reduce_qkv(const float* __restrict__ part,
                                                    float* __restrict__ q,
                                                    float* __restrict__ k,
                                                    float* __restrict__ v) {
    const long mn = 262144;
    int w = blockIdx.y;
    long idx = ((long)blockIdx.x * 256 + threadIdx.x) * 4;
    float4 a = *(const float4*)(part + (size_t)(2 * w) * mn + idx);
    float4 b = *(const float4*)(part + (size_t)(2 * w + 1) * mn + idx);
    float* C = w == 0 ? q : (w == 1 ? k : v);
    *(float4*)(C + idx) = make_float4(a.x + b.x, a.y + b.y, a.z + b.z, a.w + b.w);
}

// ---------------------------------------------------------------------------
// RMSNorm rows of x[M,N]
// ---------------------------------------------------------------------------
__global__ __launch_bounds__(256) void k_rms(const float* __restrict__ x,
                                             const float* __restrict__ g,
                                             float* __restrict__ y, int N) {
    int row = blockIdx.x;
    const float* xr = x + (size_t)row * N;
    int tid = threadIdx.x;
    float s = 0.f;
    for (int i = tid; i < N; i += 256) { float v = xr[i]; s += v * v; }
#pragma unroll
    for (int off = 32; off; off >>= 1) s += __shfl_xor(s, off);
    __shared__ float red[4];
    if ((tid & 63) == 0) red[tid >> 6] = s;
    __syncthreads();
    s = red[0] + red[1] + red[2] + red[3];
    float r = 1.0f / sqrtf(s / (float)N + 1e-6f);
    for (int i = tid; i < N; i += 256) y[(size_t)row * N + i] = xr[i] * r * g[i];
}

// ---------------------------------------------------------------------------
// Fused qk-norm + RoPE for q AND k (blockIdx.y picks buffer)
// ---------------------------------------------------------------------------
__global__ void k_qkrope2(float* __restrict__ q, float* __restrict__ k,
                          const float* __restrict__ gq, const float* __restrict__ gk) {
    int bid = blockIdx.x;
    int t = bid >> 3, h = bid & 7;
    int d = threadIdx.x;
    float* p = (blockIdx.y == 0 ? q : k) + (size_t)t * D_DIM + h * HD;
    const float* g = blockIdx.y == 0 ? gq : gk;
    float val = p[d];
    float s = val * val;
#pragma unroll
    for (int off = 32; off; off >>= 1) s += __shfl_xor(s, off);
    float r = 1.0f / sqrtf(s * (1.0f / 64.0f) + 1e-6f);
    float y = val * r * g[d];
    int dm = d & 31;
    double inv = pow(10000.0, -(double)dm / 32.0);
    double ang = (double)t * inv;
    float c = (float)cos(ang);
    float sn = (float)sin(ang);
    float partner = __shfl_xor(y, 32);
    float out = (d < 32) ? (y * c - partner * sn) : (y * c + partner * sn);
    p[d] = out;
}

// ---------------------------------------------------------------------------
// Causal attention, one block per (t, h)
// ---------------------------------------------------------------------------
__global__ __launch_bounds__(256) void k_attn(const float* __restrict__ q,
                                              const float* __restrict__ k,
                                              const float* __restrict__ v,
                                              float* __restrict__ o) {
    int bid = blockIdx.x;
    int t = bid >> 3, h = bid & 7;
    __shared__ float qs[64];
    __shared__ float sc[T_LEN];
    __shared__ float red[8];
    int tid = threadIdx.x;
    if (tid < 64) qs[tid] = q[(size_t)t * D_DIM + h * HD + tid];
    __syncthreads();
    int nk = t + 1;
    for (int kk = tid; kk < nk; kk += 256) {
        const float* kr = k + (size_t)kk * D_DIM + h * HD;
        float dot = 0.f;
#pragma unroll
        for (int d = 0; d < HD; d++) dot += qs[d] * kr[d];
        sc[kk] = dot * 0.125f;
    }
    __syncthreads();
    float m = -3.4e38f;
    for (int i = tid; i < nk; i += 256) m = fmaxf(m, sc[i]);
#pragma unroll
    for (int off = 32; off; off >>= 1) m = fmaxf(m, __shfl_xor(m, off));
    if ((tid & 63) == 0) red[tid >> 6] = m;
    __syncthreads();
    m = fmaxf(fmaxf(red[0], red[1]), fmaxf(red[2], red[3]));
    float ssum = 0.f;
    for (int i = tid; i < nk; i += 256) { float e = expf(sc[i] - m); sc[i] = e; ssum += e; }
#pragma unroll
    for (int off = 32; off; off >>= 1) ssum += __shfl_xor(ssum, off);
    if ((tid & 63) == 0) red[4 + (tid >> 6)] = ssum;
    __syncthreads();
    ssum = red[4] + red[5] + red[6] + red[7];
    float inv = 1.0f / ssum;
    int d = tid & 63, part = tid >> 6;
    float a0 = 0.f;
    for (int i = part; i < nk; i += 4) a0 += sc[i] * v[(size_t)i * D_DIM + h * HD + d];
    __syncthreads();
    sc[part * 64 + d] = a0;
    __syncthreads();
    if (tid < 64) {
        float r = (sc[tid] + sc[64 + tid] + sc[128 + tid] + sc[192 + tid]) * inv;
        o[(size_t)t * D_DIM + h * HD + tid] = r;
    }
}

// ---------------------------------------------------------------------------
// Final conv: Cin=32 -> 1, K=7 SAME, clip
// ---------------------------------------------------------------------------
__global__ __launch_bounds__(256) void k_conv_fin(const float* __restrict__ x,
                                                  const float* __restrict__ w,
                                                  const float* __restrict__ b,
                                                  float* __restrict__ y, int n) {
    __shared__ float xs[262 * 33];
    __shared__ float wsm[224];
    int tid = threadIdx.x;
    int o0 = blockIdx.x * 256;
    for (int i = tid; i < 262 * 32; i += 256) {
        int r = i >> 5, c = i & 31;
        int t = o0 - 3 + r;
        xs[r * 33 + c] = (t >= 0 && t < n) ? x[(size_t)t * 32 + c] : 0.f;
    }
    if (tid < 224) wsm[tid] = w[tid];
    __syncthreads();
    float acc = b[0];
#pragma unroll
    for (int kk = 0; kk < 7; kk++)
#pragma unroll
        for (int ci = 0; ci < 32; ci++)
            acc += xs[(tid + kk) * 33 + ci] * wsm[kk * 32 + ci];
    y[o0 + tid] = fminf(fmaxf(acc, -1.f), 1.f);
}

// ---------------------------------------------------------------------------
// Host helpers
// ---------------------------------------------------------------------------
template <int TM, int TN>
static inline void launch_gemm(hipStream_t st, const float* A, int lda, const float* B,
                               const float* bias, unsigned bmask, const float* res,
                               const float* scale, float* C, float* part,
                               int M, int N, int K, int S, int act) {
    long mn = (long)M * N;
    if (S > 1) {
        k_gemm3<TM, TN><<<dim3(M / TM, N / TN, S), 256, 0, st>>>(
            A, lda, B, nullptr, 0, nullptr, nullptr, nullptr, part, mn, N, K / S, 0);
        k_reduce<<<dim3((int)(mn / 1024)), 256, 0, st>>>(
            part, mn, S, bias, bmask, res, scale, C, N, act);
    } else {
        k_gemm3<TM, TN><<<dim3(M / TM, N / TN, 1), 256, 0, st>>>(
            A, lda, B, bias, bmask, res, scale, C, nullptr, mn, N, K, act);
    }
}

extern "C" void kernel_launch(void* const* d_in, const int* in_sizes, int n_in,
                              void* d_out, int out_size, void* d_ws, size_t ws_size,
                              hipStream_t stream) {
    int i = 0;
    const int*   codes     = (const int*)  d_in[i++];
    const float* emb_first = (const float*)d_in[i++];
    const float* pf_w      = (const float*)d_in[i++];
    const float* pf_b      = (const float*)d_in[i++];
    const float* fo_w      = (const float*)d_in[i++];
    const float* fo_b      = (const float*)d_in[i++];
    const float* emb_rest  = (const float*)d_in[i++];
    const float* pr_w      = (const float*)d_in[i++];
    const float* pr_b      = (const float*)d_in[i++];
    const float* ro_w      = (const float*)d_in[i++];
    const float* ro_b      = (const float*)d_in[i++];
    const float* pre_w     = (const float*)d_in[i++];
    const float* pre_b     = (const float*)d_in[i++];
    const float* in_w      = (const float*)d_in[i++];
    const float* in_b      = (const float*)d_in[i++];
    const float* ln1       = (const float*)d_in[i++];
    const float* qw        = (const float*)d_in[i++];
    const float* kw        = (const float*)d_in[i++];
    const float* vw        = (const float*)d_in[i++];
    const float* ow        = (const float*)d_in[i++];
    const float* qn        = (const float*)d_in[i++];
    const float* kn        = (const float*)d_in[i++];
    const float* ls_a      = (const float*)d_in[i++];
    const float* ln2       = (const float*)d_in[i++];
    const float* w1        = (const float*)d_in[i++];
    const float* w2        = (const float*)d_in[i++];
    const float* ls_m      = (const float*)d_in[i++];
    const float* fn_w      = (const float*)d_in[i++];
    const float* out_w     = (const float*)d_in[i++];
    const float* out_b     = (const float*)d_in[i++];
    const float* up_w      = (const float*)d_in[i++];
    const float* up_b      = (const float*)d_in[i++];
    const float* dec0_w    = (const float*)d_in[i++];
    const float* dec0_b    = (const float*)d_in[i++];
    const float* dw1       = (const float*)d_in[i++];
    const float* db1       = (const float*)d_in[i++];
    const float* dw2       = (const float*)d_in[i++];
    const float* db2       = (const float*)d_in[i++];
    const float* dw3       = (const float*)d_in[i++];
    const float* db3       = (const float*)d_in[i++];
    const float* dw4       = (const float*)d_in[i++];
    const float* db4       = (const float*)d_in[i++];
    const float* fin_w     = (const float*)d_in[i++];
    const float* fin_b     = (const float*)d_in[i++];

    float* ws = (float*)d_ws;
    float* outp = (float*)d_out;

    float* qf_pre   = ws + WS_QFPRE;
    float* G        = ws + WS_G;
    float* qf       = ws + WS_QF;
    float* tA       = ws + WS_TA;
    float* hidden   = ws + WS_HID;
    float* conv_out = ws + WS_CONV;
    float* h        = ws + WS_H;
    float* x        = ws + WS_X;
    float* qb       = ws + WS_QB;
    float* kb       = ws + WS_KB;
    float* vb       = ws + WS_VB;
    float* attnb    = ws + WS_ATT;
    float* ff       = ws + WS_FF;
    float* bias_sum = ws + WS_BSUM;
    float* houtp    = ws + WS_HOUT;
    float* up_out   = ws + WS_UP;
    float* dec0_out = ws + WS_DEC0;
    float* t1       = ws + WS_T1;
    float* t2       = ws + WS_T2;
    float* t3       = ws + WS_T3;
    float* t4       = ws + WS_T4;
    float* W2up     = ws + WS_W2UP;
    float* W2d1     = ws + WS_W2D1;
    float* W2d2     = ws + WS_W2D2;
    float* W2d3     = ws + WS_W2D3;
    float* W2d4     = ws + WS_W2D4;
    float* part     = ws + WS_PART;

    // --- prep ---
    k_zero_guards<<<13, 256, 0, stream>>>(ws);
    k_wt<<<24576, 256, 0, stream>>>(up_w, W2up, 1024, 1024, 2, 2);
    k_wt<<<12288, 256, 0, stream>>>(dw1, W2d1, 512, 256, 8, 11);
    k_wt<<<2304, 256, 0, stream>>>(dw2, W2d2, 256, 128, 6, 8);
    k_wt<<<480, 256, 0, stream>>>(dw3, W2d3, 128, 64, 5, 7);
    k_wt<<<96, 256, 0, stream>>>(dw4, W2d4, 64, 32, 4, 5);

    // --- RVQ decode ---
    k_gather<<<8192, 256, 0, stream>>>(codes, emb_first, emb_rest, qf_pre, G);
    k_bias_sum<<<4, 256, 0, stream>>>(pr_b, bias_sum);
    launch_gemm<64, 64>(stream, qf_pre, 256, pf_w, pf_b, ~0u, nullptr, nullptr, tA, part,
                        512, 1024, 256, 2, 0);
    launch_gemm<64, 64>(stream, tA, 1024, fo_w, fo_b, ~0u, nullptr, nullptr, qf, part,
                        512, 1024, 1024, 4, 0);
    launch_gemm<64, 64>(stream, G, 3840, pr_w, bias_sum, ~0u, nullptr, nullptr, tA, part,
                        512, 1024, 3840, 8, 0);
    launch_gemm<64, 64>(stream, tA, 1024, ro_w, ro_b, ~0u, qf, nullptr, hidden, part,
                        512, 1024, 1024, 4, 0);

    // --- causal pre-conv (k=3) via windowed GEMM ---
    launch_gemm<64, 64>(stream, hidden - 2048, 1024, pre_w, pre_b, ~0u, nullptr, nullptr,
                        conv_out, part, 512, 1024, 3072, 8, 0);

    // --- transformer input proj ---
    launch_gemm<64, 64>(stream, conv_out, 1024, in_w, in_b, ~0u, nullptr, nullptr, h, part,
                        512, 512, 1024, 4, 0);

    // --- 8 transformer layers ---
    for (int l = 0; l < NL; l++) {
        const float* qw_l = qw + (size_t)l * D_DIM * D_DIM;
        const float* kw_l = kw + (size_t)l * D_DIM * D_DIM;
        const float* vw_l = vw + (size_t)l * D_DIM * D_DIM;
        const float* ow_l = ow + (size_t)l * D_DIM * D_DIM;
        const float* w1_l = w1 + (size_t)l * D_DIM * FF_D;
        const float* w2_l = w2 + (size_t)l * FF_D * D_DIM;

        k_rms<<<512, 256, 0, stream>>>(h, ln1 + l * D_DIM, x, D_DIM);
        k_qkv<<<dim3(8, 8, 6), 256, 0, stream>>>(x, qw_l, kw_l, vw_l, part);
        k_reduce_qkv<<<dim3(256, 3), 256, 0, stream>>>(part, qb, kb, vb);
        k_qkrope2<<<dim3(T_LEN * NH, 2), 64, 0, stream>>>(qb, kb, qn + l * HD, kn + l * HD);
        k_attn<<<T_LEN * NH, 256, 0, stream>>>(qb, kb, vb, attnb);
        launch_gemm<64, 64>(stream, attnb, 512, ow_l, nullptr, 0, h, ls_a + l * D_DIM, h, part,
                            512, 512, 512, 2, 0);
        k_rms<<<512, 256, 0, stream>>>(h, ln2 + l * D_DIM, x, D_DIM);
        launch_gemm<64, 128>(stream, x, 512, w1_l, nullptr, 0, nullptr, nullptr, ff, part,
                             512, 2048, 512, 2, 1);
        launch_gemm<64, 64>(stream, ff, 2048, w2_l, nullptr, 0, h, ls_m + l * D_DIM, h, part,
                            512, 512, 2048, 8, 0);
    }

    // --- final norm + out proj ---
    k_rms<<<512, 256, 0, stream>>>(h, fn_w, x, D_DIM);
    launch_gemm<64, 64>(stream, x, 512, out_w, out_b, ~0u, nullptr, nullptr, houtp, part,
                        512, 1024, 512, 4, 0);

    // --- upsample x2 convT as GEMM, elu ---
    launch_gemm<64, 128>(stream, houtp - 1024, 1024, W2up, up_b, 1023u, nullptr, nullptr,
                         up_out, part, 512, 2048, 3072, 4, 2);

    // --- dec0 conv k=7 SAME via windowed GEMM, elu ---
    launch_gemm<128, 64>(stream, up_out - 3072, 1024, dec0_w, dec0_b, ~0u, nullptr, nullptr,
                         dec0_out, part, 1024, 512, 7168, 8, 2);

    // --- SEANet convT chain as GEMMs, elu ---
    launch_gemm<128, 128>(stream, dec0_out - 512, 512, W2d1, db1, 255u, nullptr, nullptr,
                          t1, part, 1024, 2048, 1536, 2, 2);
    launch_gemm<128, 128>(stream, t1 - 256, 256, W2d2, db2, 127u, nullptr, nullptr,
                          t2, nullptr, 8192, 768, 768, 1, 2);
    launch_gemm<128, 64>(stream, t2 - 128, 128, W2d3, db3, 63u, nullptr, nullptr,
                         t3, nullptr, 49152, 320, 384, 1, 2);
    launch_gemm<128, 128>(stream, t3 - 64, 64, W2d4, db4, 31u, nullptr, nullptr,
                          t4, nullptr, 245760, 128, 192, 1, 2);

    // --- final conv ---
    k_conv_fin<<<983040 / 256, 256, 0, stream>>>(t4, fin_w, fin_b, outp, 983040);
}

// Round 6
// 3687.330 us; speedup vs baseline: 1.0900x; 1.0900x over previous
//
#include <hip/hip_runtime.h>
#include <hip/hip_bf16.h>
#include <math.h>

#define T_LEN 512
#define LAT   1024
#define D_DIM 512
#define NH    8
#define HD    64
#define FF_D  2048
#define NL    8
#define NQ    16

// ---------------------------------------------------------------------------
// Workspace layout (float offsets)
// ---------------------------------------------------------------------------
#define WS_QFPRE    0
#define WS_G        131072
#define WS_QF       2097152
#define WS_TA       2621440
#define WS_HIDG     3145728            // 2048 guard floats before hidden
#define WS_HID      3147776
#define WS_CONV     3672064
#define WS_H        4196352
#define WS_X        4458496
#define WS_QB       4720640
#define WS_KB       4982784
#define WS_VB       5244928
#define WS_ATT      5507072
#define WS_FF       5769216
#define WS_BSUM     6817792
#define WS_HOUT     6819840            // guard 1024 at 6818816, post at 7344128
#define WS_UP       7348224            // guard 3072 at 7345152, post at 8396800
#define WS_DEC0     8400384            // guard 512  at 8399872, post at 8924672
#define WS_T1       8925440            // guard 256  at 8925184, post at 11022592
#define WS_T2       11022976           // guard 128  at 11022848, post at 17314432
#define WS_W2UP     17314560           // 6291456
#define WS_W2D1     23606016           // 3145728
#define WS_W2D2     26751744           // 589824
#define WS_W2D3     27341568           // 122880
#define WS_T3       31457344           // guard 64 at 31457280, post at 47185984
#define WS_W2D4     47186048           // 24576 -> ends 47210624
#define WS_T4       0                  // aliases phase-A region (dead by then)
#define WS_PART     31457344           // split-K partials alias t3 data region

// ---------------------------------------------------------------------------
// Zero the guard rows (ws is poisoned 0xAA before every launch)
// ---------------------------------------------------------------------------
__global__ void k_zero_guards(float* __restrict__ ws) {
    const int offs[13] = {3145728, 6818816, 7344128, 7345152, 8396800,
                          8399872, 8924672, 8925184, 11022592, 11022848,
                          17314432, 31457280, 47185984};
    const int lens[13] = {2048, 1024, 1024, 3072, 3072,
                          512, 512, 256, 256, 128,
                          128, 64, 64};
    int r = blockIdx.x;
    for (int i = threadIdx.x; i < lens[r]; i += 256) ws[offs[r] + i] = 0.f;
}

// ---------------------------------------------------------------------------
// Gathers
// ---------------------------------------------------------------------------
__global__ __launch_bounds__(256) void k_gather(const int* __restrict__ codes,
                                                const float* __restrict__ emb_first,
                                                const float* __restrict__ emb_rest,
                                                float* __restrict__ qf_pre,
                                                float* __restrict__ G) {
    int idx = blockIdx.x * 256 + threadIdx.x;
    int c = idx & 255;
    int r = (idx >> 8) & 15;
    int t = idx >> 12;
    if (t >= T_LEN) return;
    if (r == 0) {
        int code = codes[t];
        qf_pre[t * 256 + c] = emb_first[code * 256 + c];
    } else {
        int n = r - 1;
        int code = codes[(n + 1) * T_LEN + t];
        G[t * 3840 + n * 256 + c] = emb_rest[(n * 2048 + code) * 256 + c];
    }
}

__global__ void k_bias_sum(const float* __restrict__ pr_b, float* __restrict__ out) {
    int d = blockIdx.x * 256 + threadIdx.x;
    if (d >= LAT) return;
    float s = 0.f;
    for (int n = 0; n < NQ - 1; n++) s += pr_b[n * LAT + d];
    out[d] = s;
}

// ---------------------------------------------------------------------------
// convT weight transform (K=2s): W2[(j*Cin+ci), p*Cout+co], j in 0..2 (d=j-1)
// ---------------------------------------------------------------------------
__global__ __launch_bounds__(256) void k_wt(const float* __restrict__ w,
                                            float* __restrict__ W2,
                                            int Cin, int Cout, int s, int pad_a) {
    int idx = blockIdx.x * 256 + threadIdx.x;
    int N = s * Cout;
    int total = 3 * Cin * N;
    if (idx >= total) return;
    int col = idx % N;
    int rowk = idx / N;
    int j = rowk / Cin, ci = rowk % Cin;
    int p = col / Cout, co = col % Cout;
    int kk0 = (pad_a - p) % s;
    if (kk0 < 0) kk0 += s;
    int cp = (p + kk0 - pad_a) / s;
    int d = j - 1;
    float v = 0.f;
    if (d == cp) v = w[((size_t)kk0 * Cin + ci) * Cout + co];
    else if (d == cp + 1) v = w[((size_t)(kk0 + s) * Cin + ci) * Cout + co];
    W2[idx] = v;
}

// ---------------------------------------------------------------------------
// GEMM core v3: TM x TN tile, 256 threads, QUADRANT microtile:
// thread rows  = { q*(TM/2) + ty*4 + 0..3 : q < RM/4 }
// thread cols  = { q*(TN/2) + tx*4 + 0..3 : q < RN/4 }
// -> all LDS fragment reads are float4 at 4-float lane stride (<=2-way, free).
// Double-buffered LDS, float4 global staging, BK=16, one barrier per k-step.
// ---------------------------------------------------------------------------
template <int TM, int TN>
__device__ __forceinline__ void gemm_core2(const float* __restrict__ A, int lda,
                                           const float* __restrict__ B, int N,
                                           int klen, int m0, int n0,
                                           float (&acc)[TM / 16][TN / 16]) {
    constexpr int RM = TM / 16, RN = TN / 16;
    constexpr int QM = RM / 4, QN = RN / 4;   // quadrant counts (1 or 2)
    constexpr int NA4 = TM / 64;
    constexpr int NB4 = TN / 64;
    constexpr int BCQ = TN / 4;
    __shared__ float As[2][16][TM + 4];
    __shared__ float Bs[2][16][TN + 4];
    int tid = threadIdx.x;
    int tx = tid & 15, ty = tid >> 4;
    int arow[NA4], akq[NA4], bkk[NB4], bcq[NB4];
#pragma unroll
    for (int i = 0; i < NA4; i++) {
        int idx = tid + 256 * i;
        arow[i] = idx >> 2; akq[i] = idx & 3;
    }
#pragma unroll
    for (int i = 0; i < NB4; i++) {
        int idx = tid + 256 * i;
        bkk[i] = idx / BCQ; bcq[i] = idx % BCQ;
    }
    float4 av[NA4], bv[NB4];
#pragma unroll
    for (int i = 0; i < NA4; i++)
        av[i] = *(const float4*)&A[(size_t)(m0 + arow[i]) * lda + akq[i] * 4];
#pragma unroll
    for (int i = 0; i < NB4; i++)
        bv[i] = *(const float4*)&B[(size_t)bkk[i] * N + n0 + bcq[i] * 4];
#pragma unroll
    for (int i = 0; i < NA4; i++) {
        As[0][akq[i] * 4 + 0][arow[i]] = av[i].x;
        As[0][akq[i] * 4 + 1][arow[i]] = av[i].y;
        As[0][akq[i] * 4 + 2][arow[i]] = av[i].z;
        As[0][akq[i] * 4 + 3][arow[i]] = av[i].w;
    }
#pragma unroll
    for (int i = 0; i < NB4; i++)
        *(float4*)&Bs[0][bkk[i]][bcq[i] * 4] = bv[i];
    __syncthreads();
    int nk = klen >> 4;
    for (int t = 0; t < nk; t++) {
        int cur = t & 1;
        if (t + 1 < nk) {
            int k0 = (t + 1) << 4;
#pragma unroll
            for (int i = 0; i < NA4; i++)
                av[i] = *(const float4*)&A[(size_t)(m0 + arow[i]) * lda + k0 + akq[i] * 4];
#pragma unroll
            for (int i = 0; i < NB4; i++)
                bv[i] = *(const float4*)&B[(size_t)(k0 + bkk[i]) * N + n0 + bcq[i] * 4];
        }
#pragma unroll
        for (int kk = 0; kk < 16; kk++) {
            float a[RM], b[RN];
#pragma unroll
            for (int q = 0; q < QM; q++)
                *(float4*)&a[4 * q] = *(const float4*)&As[cur][kk][q * (TM / 2) + ty * 4];
#pragma unroll
            for (int q = 0; q < QN; q++)
                *(float4*)&b[4 * q] = *(const float4*)&Bs[cur][kk][q * (TN / 2) + tx * 4];
#pragma unroll
            for (int i = 0; i < RM; i++)
#pragma unroll
                for (int j = 0; j < RN; j++) acc[i][j] += a[i] * b[j];
        }
        if (t + 1 < nk) {
            int nxt = cur ^ 1;
#pragma unroll
            for (int i = 0; i < NA4; i++) {
                As[nxt][akq[i] * 4 + 0][arow[i]] = av[i].x;
                As[nxt][akq[i] * 4 + 1][arow[i]] = av[i].y;
                As[nxt][akq[i] * 4 + 2][arow[i]] = av[i].z;
                As[nxt][akq[i] * 4 + 3][arow[i]] = av[i].w;
            }
#pragma unroll
            for (int i = 0; i < NB4; i++)
                *(float4*)&Bs[nxt][bkk[i]][bcq[i] * 4] = bv[i];
            __syncthreads();
        }
    }
}

__device__ __forceinline__ float apply_act(float v, int act) {
    if (act == 1) return 0.5f * v * (1.0f + erff(v * 0.70710678118654752440f));
    if (act == 2) return v > 0.f ? v : expm1f(v);
    return v;
}

// If part != null: raw partial write to part + z*mn (epilogue in k_reduce).
template <int TM, int TN>
__global__ __launch_bounds__(256) void k_gemm3(const float* __restrict__ A, int lda,
                                               const float* __restrict__ B,
                                               const float* __restrict__ bias, unsigned bmask,
                                               const float* __restrict__ res,
                                               const float* __restrict__ scale,
                                               float* __restrict__ C,
                                               float* __restrict__ part, long mn,
                                               int N, int klen, int act) {
    constexpr int RM = TM / 16, RN = TN / 16;
    constexpr int QN = RN / 4;
    float acc[RM][RN] = {};
    int m0 = blockIdx.x * TM, n0 = blockIdx.y * TN;
    int kz = blockIdx.z * klen;
    gemm_core2<TM, TN>(A + kz, lda, B + (size_t)kz * N, N, klen, m0, n0, acc);
    int tid = threadIdx.x;
    int tx = tid & 15, ty = tid >> 4;
    if (part) {
        float* out = part + (size_t)blockIdx.z * mn;
#pragma unroll
        for (int i = 0; i < RM; i++) {
            int row = m0 + ((i >> 2) * (TM / 2)) + ty * 4 + (i & 3);
            size_t rb = (size_t)row * N;
#pragma unroll
            for (int q = 0; q < QN; q++)
                *(float4*)&out[rb + n0 + q * (TN / 2) + tx * 4] =
                    make_float4(acc[i][4 * q], acc[i][4 * q + 1],
                                acc[i][4 * q + 2], acc[i][4 * q + 3]);
        }
    } else {
#pragma unroll
        for (int i = 0; i < RM; i++) {
            int row = m0 + ((i >> 2) * (TM / 2)) + ty * 4 + (i & 3);
            size_t rb = (size_t)row * N;
#pragma unroll
            for (int j = 0; j < RN; j++) {
                int col = n0 + ((j >> 2) * (TN / 2)) + tx * 4 + (j & 3);
                float v = acc[i][j];
                if (bias) v += bias[col & bmask];
                v = apply_act(v, act);
                if (scale) v *= scale[col];
                if (res) v += res[rb + col];
                acc[i][j] = v;
            }
#pragma unroll
            for (int q = 0; q < QN; q++)
                *(float4*)&C[rb + n0 + q * (TN / 2) + tx * 4] =
                    make_float4(acc[i][4 * q], acc[i][4 * q + 1],
                                acc[i][4 * q + 2], acc[i][4 * q + 3]);
        }
    }
}

// Fused QKV with split-K=2: z = which*2 + s; raw partials. 64x64 (QM=QN=1).
__global__ __launch_bounds__(256) void k_qkv(const float* __restrict__ A,
                                             const float* __restrict__ B0,
                                             const float* __restrict__ B1,
                                             const float* __restrict__ B2,
                                             float* __restrict__ part) {
    int which = blockIdx.z >> 1, s = blockIdx.z & 1;
    const float* B = which == 0 ? B0 : (which == 1 ? B1 : B2);
    float acc[4][4] = {};
    int m0 = blockIdx.x * 64, n0 = blockIdx.y * 64;
    int kz = s * 256;
    gemm_core2<64, 64>(A + kz, 512, B + (size_t)kz * 512, 512, 256, m0, n0, acc);
    int tid = threadIdx.x;
    int tx = tid & 15, ty = tid >> 4;
    float* out = part + (size_t)blockIdx.z * (512 * 512);
#pragma unroll
    for (int i = 0; i < 4; i++)
        *(float4*)&out[(size_t)(m0 + ty * 4 + i) * 512 + n0 + tx * 4] =
            make_float4(acc[i][0], acc[i][1], acc[i][2], acc[i][3]);
}

// ---------------------------------------------------------------------------
// Split-K reduce + epilogue (bias -> act -> scale -> res)
// ---------------------------------------------------------------------------
__global__ __launch_bounds__(256) void k_reduce(const float* __restrict__ part, long mn, int S,
                                                const float* __restrict__ bias, unsigned bmask,
                                                const float* __restrict__ res,
                                                const float* __restrict__ scale,
                                                float* __restrict__ C, int N, int act) {
    long idx = ((long)blockIdx.x * 256 + threadIdx.x) * 4;
    if (idx >= mn) return;
    float4 v = *(const float4*)(part + idx);
    for (int s2 = 1; s2 < S; s2++) {
        float4 u = *(const float4*)(part + (size_t)s2 * mn + idx);
        v.x += u.x; v.y += u.y; v.z += u.z; v.w += u.w;
    }
    int col = (int)(idx % N);
    float vv[4] = {v.x, v.y, v.z, v.w};
#pragma unroll
    for (int j = 0; j < 4; j++) {
        float t = vv[j];
        int c = col + j;
        if (bias) t += bias[c & bmask];
        t = apply_act(t, act);
        if (scale) t *= scale[c];
        if (res) t += res[idx + j];
        vv[j] = t;
    }
    *(float4*)(C + idx) = make_float4(vv[0], vv[1], vv[2], vv[3]);
}

__global__ __launch_bounds__(256) void k_reduce_qkv(const float* __restrict__ part,
                                                    float* __restrict__ q,
                                                    float* __restrict__ k,
                                                    float* __restrict__ v) {
    const long mn = 262144;
    int w = blockIdx.y;
    long idx = ((long)blockIdx.x * 256 + threadIdx.x) * 4;
    float4 a = *(const float4*)(part + (size_t)(2 * w) * mn + idx);
    float4 b = *(const float4*)(part + (size_t)(2 * w + 1) * mn + idx);
    float* C = w == 0 ? q : (w == 1 ? k : v);
    *(float4*)(C + idx) = make_float4(a.x + b.x, a.y + b.y, a.z + b.z, a.w + b.w);
}

// ---------------------------------------------------------------------------
// RMSNorm rows of x[M,N]
// ---------------------------------------------------------------------------
__global__ __launch_bounds__(256) void k_rms(const float* __restrict__ x,
                                             const float* __restrict__ g,
                                             float* __restrict__ y, int N) {
    int row = blockIdx.x;
    const float* xr = x + (size_t)row * N;
    int tid = threadIdx.x;
    float s = 0.f;
    for (int i = tid; i < N; i += 256) { float v = xr[i]; s += v * v; }
#pragma unroll
    for (int off = 32; off; off >>= 1) s += __shfl_xor(s, off);
    __shared__ float red[4];
    if ((tid & 63) == 0) red[tid >> 6] = s;
    __syncthreads();
    s = red[0] + red[1] + red[2] + red[3];
    float r = 1.0f / sqrtf(s / (float)N + 1e-6f);
    for (int i = tid; i < N; i += 256) y[(size_t)row * N + i] = xr[i] * r * g[i];
}

// ---------------------------------------------------------------------------
// Fused qk-norm + RoPE for q AND k (blockIdx.y picks buffer)
// ---------------------------------------------------------------------------
__global__ void k_qkrope2(float* __restrict__ q, float* __restrict__ k,
                          const float* __restrict__ gq, const float* __restrict__ gk) {
    int bid = blockIdx.x;
    int t = bid >> 3, h = bid & 7;
    int d = threadIdx.x;
    float* p = (blockIdx.y == 0 ? q : k) + (size_t)t * D_DIM + h * HD;
    const float* g = blockIdx.y == 0 ? gq : gk;
    float val = p[d];
    float s = val * val;
#pragma unroll
    for (int off = 32; off; off >>= 1) s += __shfl_xor(s, off);
    float r = 1.0f / sqrtf(s * (1.0f / 64.0f) + 1e-6f);
    float y = val * r * g[d];
    int dm = d & 31;
    double inv = pow(10000.0, -(double)dm / 32.0);
    double ang = (double)t * inv;
    float c = (float)cos(ang);
    float sn = (float)sin(ang);
    float partner = __shfl_xor(y, 32);
    float out = (d < 32) ? (y * c - partner * sn) : (y * c + partner * sn);
    p[d] = out;
}

// ---------------------------------------------------------------------------
// Causal attention, one block per (t, h)
// ---------------------------------------------------------------------------
__global__ __launch_bounds__(256) void k_attn(const float* __restrict__ q,
                                              const float* __restrict__ k,
                                              const float* __restrict__ v,
                                              float* __restrict__ o) {
    int bid = blockIdx.x;
    int t = bid >> 3, h = bid & 7;
    __shared__ float qs[64];
    __shared__ float sc[T_LEN];
    __shared__ float red[8];
    int tid = threadIdx.x;
    if (tid < 64) qs[tid] = q[(size_t)t * D_DIM + h * HD + tid];
    __syncthreads();
    int nk = t + 1;
    for (int kk = tid; kk < nk; kk += 256) {
        const float* kr = k + (size_t)kk * D_DIM + h * HD;
        float dot = 0.f;
#pragma unroll
        for (int d = 0; d < HD; d++) dot += qs[d] * kr[d];
        sc[kk] = dot * 0.125f;
    }
    __syncthreads();
    float m = -3.4e38f;
    for (int i = tid; i < nk; i += 256) m = fmaxf(m, sc[i]);
#pragma unroll
    for (int off = 32; off; off >>= 1) m = fmaxf(m, __shfl_xor(m, off));
    if ((tid & 63) == 0) red[tid >> 6] = m;
    __syncthreads();
    m = fmaxf(fmaxf(red[0], red[1]), fmaxf(red[2], red[3]));
    float ssum = 0.f;
    for (int i = tid; i < nk; i += 256) { float e = expf(sc[i] - m); sc[i] = e; ssum += e; }
#pragma unroll
    for (int off = 32; off; off >>= 1) ssum += __shfl_xor(ssum, off);
    if ((tid & 63) == 0) red[4 + (tid >> 6)] = ssum;
    __syncthreads();
    ssum = red[4] + red[5] + red[6] + red[7];
    float inv = 1.0f / ssum;
    int d = tid & 63, part = tid >> 6;
    float a0 = 0.f;
    for (int i = part; i < nk; i += 4) a0 += sc[i] * v[(size_t)i * D_DIM + h * HD + d];
    __syncthreads();
    sc[part * 64 + d] = a0;
    __syncthreads();
    if (tid < 64) {
        float r = (sc[tid] + sc[64 + tid] + sc[128 + tid] + sc[192 + tid]) * inv;
        o[(size_t)t * D_DIM + h * HD + tid] = r;
    }
}

// ---------------------------------------------------------------------------
// Final conv: Cin=32 -> 1, K=7 SAME, clip
// ---------------------------------------------------------------------------
__global__ __launch_bounds__(256) void k_conv_fin(const float* __restrict__ x,
                                                  const float* __restrict__ w,
                                                  const float* __restrict__ b,
                                                  float* __restrict__ y, int n) {
    __shared__ float xs[262 * 33];
    __shared__ float wsm[224];
    int tid = threadIdx.x;
    int o0 = blockIdx.x * 256;
    for (int i = tid; i < 262 * 32; i += 256) {
        int r = i >> 5, c = i & 31;
        int t = o0 - 3 + r;
        xs[r * 33 + c] = (t >= 0 && t < n) ? x[(size_t)t * 32 + c] : 0.f;
    }
    if (tid < 224) wsm[tid] = w[tid];
    __syncthreads();
    float acc = b[0];
#pragma unroll
    for (int kk = 0; kk < 7; kk++)
#pragma unroll
        for (int ci = 0; ci < 32; ci++)
            acc += xs[(tid + kk) * 33 + ci] * wsm[kk * 32 + ci];
    y[o0 + tid] = fminf(fmaxf(acc, -1.f), 1.f);
}

// ---------------------------------------------------------------------------
// Host helpers
// ---------------------------------------------------------------------------
template <int TM, int TN>
static inline void launch_gemm(hipStream_t st, const float* A, int lda, const float* B,
                               const float* bias, unsigned bmask, const float* res,
                               const float* scale, float* C, float* part,
                               int M, int N, int K, int S, int act) {
    long mn = (long)M * N;
    if (S > 1) {
        k_gemm3<TM, TN><<<dim3(M / TM, N / TN, S), 256, 0, st>>>(
            A, lda, B, nullptr, 0, nullptr, nullptr, nullptr, part, mn, N, K / S, 0);
        k_reduce<<<dim3((int)(mn / 1024)), 256, 0, st>>>(
            part, mn, S, bias, bmask, res, scale, C, N, act);
    } else {
        k_gemm3<TM, TN><<<dim3(M / TM, N / TN, 1), 256, 0, st>>>(
            A, lda, B, bias, bmask, res, scale, C, nullptr, mn, N, K, act);
    }
}

extern "C" void kernel_launch(void* const* d_in, const int* in_sizes, int n_in,
                              void* d_out, int out_size, void* d_ws, size_t ws_size,
                              hipStream_t stream) {
    int i = 0;
    const int*   codes     = (const int*)  d_in[i++];
    const float* emb_first = (const float*)d_in[i++];
    const float* pf_w      = (const float*)d_in[i++];
    const float* pf_b      = (const float*)d_in[i++];
    const float* fo_w      = (const float*)d_in[i++];
    const float* fo_b      = (const float*)d_in[i++];
    const float* emb_rest  = (const float*)d_in[i++];
    const float* pr_w      = (const float*)d_in[i++];
    const float* pr_b      = (const float*)d_in[i++];
    const float* ro_w      = (const float*)d_in[i++];
    const float* ro_b      = (const float*)d_in[i++];
    const float* pre_w     = (const float*)d_in[i++];
    const float* pre_b     = (const float*)d_in[i++];
    const float* in_w      = (const float*)d_in[i++];
    const float* in_b      = (const float*)d_in[i++];
    const float* ln1       = (const float*)d_in[i++];
    const float* qw        = (const float*)d_in[i++];
    const float* kw        = (const float*)d_in[i++];
    const float* vw        = (const float*)d_in[i++];
    const float* ow        = (const float*)d_in[i++];
    const float* qn        = (const float*)d_in[i++];
    const float* kn        = (const float*)d_in[i++];
    const float* ls_a      = (const float*)d_in[i++];
    const float* ln2       = (const float*)d_in[i++];
    const float* w1        = (const float*)d_in[i++];
    const float* w2        = (const float*)d_in[i++];
    const float* ls_m      = (const float*)d_in[i++];
    const float* fn_w      = (const float*)d_in[i++];
    const float* out_w     = (const float*)d_in[i++];
    const float* out_b     = (const float*)d_in[i++];
    const float* up_w      = (const float*)d_in[i++];
    const float* up_b      = (const float*)d_in[i++];
    const float* dec0_w    = (const float*)d_in[i++];
    const float* dec0_b    = (const float*)d_in[i++];
    const float* dw1       = (const float*)d_in[i++];
    const float* db1       = (const float*)d_in[i++];
    const float* dw2       = (const float*)d_in[i++];
    const float* db2       = (const float*)d_in[i++];
    const float* dw3       = (const float*)d_in[i++];
    const float* db3       = (const float*)d_in[i++];
    const float* dw4       = (const float*)d_in[i++];
    const float* db4       = (const float*)d_in[i++];
    const float* fin_w     = (const float*)d_in[i++];
    const float* fin_b     = (const float*)d_in[i++];

    float* ws = (float*)d_ws;
    float* outp = (float*)d_out;

    float* qf_pre   = ws + WS_QFPRE;
    float* G        = ws + WS_G;
    float* qf       = ws + WS_QF;
    float* tA       = ws + WS_TA;
    float* hidden   = ws + WS_HID;
    float* conv_out = ws + WS_CONV;
    float* h        = ws + WS_H;
    float* x        = ws + WS_X;
    float* qb       = ws + WS_QB;
    float* kb       = ws + WS_KB;
    float* vb       = ws + WS_VB;
    float* attnb    = ws + WS_ATT;
    float* ff       = ws + WS_FF;
    float* bias_sum = ws + WS_BSUM;
    float* houtp    = ws + WS_HOUT;
    float* up_out   = ws + WS_UP;
    float* dec0_out = ws + WS_DEC0;
    float* t1       = ws + WS_T1;
    float* t2       = ws + WS_T2;
    float* t3       = ws + WS_T3;
    float* t4       = ws + WS_T4;
    float* W2up     = ws + WS_W2UP;
    float* W2d1     = ws + WS_W2D1;
    float* W2d2     = ws + WS_W2D2;
    float* W2d3     = ws + WS_W2D3;
    float* W2d4     = ws + WS_W2D4;
    float* part     = ws + WS_PART;

    // --- prep ---
    k_zero_guards<<<13, 256, 0, stream>>>(ws);
    k_wt<<<24576, 256, 0, stream>>>(up_w, W2up, 1024, 1024, 2, 2);
    k_wt<<<12288, 256, 0, stream>>>(dw1, W2d1, 512, 256, 8, 11);
    k_wt<<<2304, 256, 0, stream>>>(dw2, W2d2, 256, 128, 6, 8);
    k_wt<<<480, 256, 0, stream>>>(dw3, W2d3, 128, 64, 5, 7);
    k_wt<<<96, 256, 0, stream>>>(dw4, W2d4, 64, 32, 4, 5);

    // --- RVQ decode ---
    k_gather<<<8192, 256, 0, stream>>>(codes, emb_first, emb_rest, qf_pre, G);
    k_bias_sum<<<4, 256, 0, stream>>>(pr_b, bias_sum);
    launch_gemm<64, 64>(stream, qf_pre, 256, pf_w, pf_b, ~0u, nullptr, nullptr, tA, part,
                        512, 1024, 256, 2, 0);
    launch_gemm<64, 64>(stream, tA, 1024, fo_w, fo_b, ~0u, nullptr, nullptr, qf, part,
                        512, 1024, 1024, 4, 0);
    launch_gemm<64, 64>(stream, G, 3840, pr_w, bias_sum, ~0u, nullptr, nullptr, tA, part,
                        512, 1024, 3840, 8, 0);
    launch_gemm<64, 64>(stream, tA, 1024, ro_w, ro_b, ~0u, qf, nullptr, hidden, part,
                        512, 1024, 1024, 4, 0);

    // --- causal pre-conv (k=3) via windowed GEMM ---
    launch_gemm<64, 64>(stream, hidden - 2048, 1024, pre_w, pre_b, ~0u, nullptr, nullptr,
                        conv_out, part, 512, 1024, 3072, 8, 0);

    // --- transformer input proj ---
    launch_gemm<64, 64>(stream, conv_out, 1024, in_w, in_b, ~0u, nullptr, nullptr, h, part,
                        512, 512, 1024, 4, 0);

    // --- 8 transformer layers ---
    for (int l = 0; l < NL; l++) {
        const float* qw_l = qw + (size_t)l * D_DIM * D_DIM;
        const float* kw_l = kw + (size_t)l * D_DIM * D_DIM;
        const float* vw_l = vw + (size_t)l * D_DIM * D_DIM;
        const float* ow_l = ow + (size_t)l * D_DIM * D_DIM;
        const float* w1_l = w1 + (size_t)l * D_DIM * FF_D;
        const float* w2_l = w2 + (size_t)l * FF_D * D_DIM;

        k_rms<<<512, 256, 0, stream>>>(h, ln1 + l * D_DIM, x, D_DIM);
        k_qkv<<<dim3(8, 8, 6), 256, 0, stream>>>(x, qw_l, kw_l, vw_l, part);
        k_reduce_qkv<<<dim3(256, 3), 256, 0, stream>>>(part, qb, kb, vb);
        k_qkrope2<<<dim3(T_LEN * NH, 2), 64, 0, stream>>>(qb, kb, qn + l * HD, kn + l * HD);
        k_attn<<<T_LEN * NH, 256, 0, stream>>>(qb, kb, vb, attnb);
        launch_gemm<64, 64>(stream, attnb, 512, ow_l, nullptr, 0, h, ls_a + l * D_DIM, h, part,
                            512, 512, 512, 2, 0);
        k_rms<<<512, 256, 0, stream>>>(h, ln2 + l * D_DIM, x, D_DIM);
        launch_gemm<64, 128>(stream, x, 512, w1_l, nullptr, 0, nullptr, nullptr, ff, part,
                             512, 2048, 512, 2, 1);
        launch_gemm<64, 64>(stream, ff, 2048, w2_l, nullptr, 0, h, ls_m + l * D_DIM, h, part,
                            512, 512, 2048, 8, 0);
    }

    // --- final norm + out proj ---
    k_rms<<<512, 256, 0, stream>>>(h, fn_w, x, D_DIM);
    launch_gemm<64, 64>(stream, x, 512, out_w, out_b, ~0u, nullptr, nullptr, houtp, part,
                        512, 1024, 512, 4, 0);

    // --- upsample x2 convT as GEMM, elu ---
    launch_gemm<64, 128>(stream, houtp - 1024, 1024, W2up, up_b, 1023u, nullptr, nullptr,
                         up_out, part, 512, 2048, 3072, 4, 2);

    // --- dec0 conv k=7 SAME via windowed GEMM, elu ---
    launch_gemm<128, 64>(stream, up_out - 3072, 1024, dec0_w, dec0_b, ~0u, nullptr, nullptr,
                         dec0_out, part, 1024, 512, 7168, 8, 2);

    // --- SEANet convT chain as GEMMs, elu ---
    launch_gemm<128, 128>(stream, dec0_out - 512, 512, W2d1, db1, 255u, nullptr, nullptr,
                          t1, part, 1024, 2048, 1536, 2, 2);
    launch_gemm<128, 128>(stream, t1 - 256, 256, W2d2, db2, 127u, nullptr, nullptr,
                          t2, nullptr, 8192, 768, 768, 1, 2);
    launch_gemm<128, 64>(stream, t2 - 128, 128, W2d3, db3, 63u, nullptr, nullptr,
                         t3, nullptr, 49152, 320, 384, 1, 2);
    launch_gemm<128, 128>(stream, t3 - 64, 64, W2d4, db4, 31u, nullptr, nullptr,
                          t4, nullptr, 245760, 128, 192, 1, 2);

    // --- final conv ---
    k_conv_fin<<<983040 / 256, 256, 0, stream>>>(t4, fin_w, fin_b, outp, 983040);
}